// Round 3
// baseline (431.680 us; speedup 1.0000x reference)
//
#include <hip/hip_runtime.h>
#include <stdint.h>

// L=S=1024, N=16, E=1024, single head. f32 in/out, bf16 MFMA internally.
//
// R7 = R6 with the K-loop restructured for intra-wave MFMA/LDS overlap:
//   - ring-4 LDS (4 x 32KB), 4 g2l/tile staged 3 ahead, vmcnt(4)/tile
//     boundary (counted, never 0)  ==> tiles <= kt+2 landed at barrier.
//   - ONE barrier per K-tile (ring-4 makes read/next-read/stage buffers
//     pairwise distinct; staged buffer's readers finished 2 barriers ago).
//   - fragment reads for tile kt+1 issued DURING tile kt's MFMA region:
//     MFMA consumes registers read last region, so compiler interleaves
//     ds_read with MFMA issue (AITER-style interleave, counted waits).
//   - manual unroll-by-2 with named frag register sets (static indexing).
// Epilogue (LDS-staged coalesced stores), XCD chunk swizzle, cvt, softmax
// unchanged from R6.

typedef __attribute__((ext_vector_type(8))) short bf16x8;   // 8 bf16 = 4 VGPRs
typedef __attribute__((ext_vector_type(4))) float f32x4;    // MFMA 16x16 accum

__device__ __forceinline__ float bf2f(unsigned short u) {
    union { unsigned int i; float f; } w; w.i = ((unsigned int)u) << 16; return w.f;
}
__device__ __forceinline__ unsigned short f2bf(float f) {
    union { float f; unsigned int i; } w; w.f = f;
    unsigned int r = (w.i + 0x7FFFu + ((w.i >> 16) & 1u)) >> 16;  // RNE
    return (unsigned short)r;
}

// async global->LDS, 16B/lane; LDS dest is wave-uniform base + lane*16B
__device__ __forceinline__ void g2l16(const unsigned short* g, unsigned short* l) {
    __builtin_amdgcn_global_load_lds(
        (const __attribute__((address_space(1))) unsigned int*)g,
        (__attribute__((address_space(3))) unsigned int*)l, 16, 0, 0);
}

#define BM 256
#define BN 256
#define BK 32

// C[m][col] = (sum_k A[m,k]*B[col,k] + bias) * scale.
// BIAS_MODE: 0 none, 1 per-col, 2 per-row. K multiple of 64, K/32 >= 4.
// Grid MUST be exactly 256 blocks (8 XCDs x 32 chunk).
template <int BIAS_MODE, typename OutT>
__global__ __launch_bounds__(512, 2) void gemm_bt2(
    const unsigned short* __restrict__ A,
    const unsigned short* __restrict__ B,
    OutT* __restrict__ C,
    const float* __restrict__ bias,
    float scale, int K,
    long lda, long ldb, long ldc,
    long aBatch, long bBatch, long cBatch,
    int gridM, int gridN)
{
    // ring: buf*16384 shorts; A tile at +0 (8192), B tile at +8192.
    __shared__ __align__(16) unsigned short lds[65536];   // 128 KiB

    const int tid  = threadIdx.x;
    const int wave = tid >> 6;      // 0..7
    const int lane = tid & 63;
    const int lr   = lane & 15;
    const int q4   = lane >> 4;
    const int wm   = wave >> 2;     // 0..1  (M half)
    const int wn   = wave & 3;      // 0..3  (N quarter)

    // chunked XCD swizzle: physical p -> logical l; XCD (p%8) owns 32
    // consecutive logical blocks; bcol-fast decode keeps panel sharers
    // on one XCD's L2.
    const int p    = blockIdx.x;
    const int l    = ((p & 7) << 5) + (p >> 3);
    const int bcol = l % gridN;
    const int t2   = l / gridN;
    const int brow = t2 % gridM;
    const int bz   = t2 / gridM;

    const long m0 = (long)brow * BM;
    const long n0 = (long)bcol * BN;
    A += (long)bz * aBatch;
    B += (long)bz * bBatch;
    C += (long)bz * cBatch;

    // staging map (R5-proven): physical chunk pc = i*512 + tid holds logical
    // chunk lc = pc ^ ((pc>>3)&7).
    const int tswz  = tid ^ ((tid >> 3) & 7);
    const int srow  = tswz >> 2;          // 0..127
    const int skoff = (tswz & 3) * 8;     // element offset in k
    const unsigned short* aS0 = A + (m0 + srow) * lda + skoff;
    const unsigned short* aS1 = A + (m0 + 128 + srow) * lda + skoff;
    const unsigned short* bS0 = B + (n0 + srow) * ldb + skoff;
    const unsigned short* bS1 = B + (n0 + 128 + srow) * ldb + skoff;
    const int ldsW = wave * 512;          // wave's 1KB slice per stage inst

    // swizzled fragment read offset (lane constant, in ushorts)
    const int myoff = (((lr << 2) | q4) ^ ((lr >> 1) & 7)) << 3;

    f32x4 acc[8][4];
    const f32x4 zero = {0.f, 0.f, 0.f, 0.f};
#pragma unroll
    for (int m = 0; m < 8; m++)
#pragma unroll
        for (int n = 0; n < 4; n++) acc[m][n] = zero;

    const int nkt = K / BK;   // 32 here (must be even, >= 4)

    // ---- prologue: stage tiles 0..2 into bufs 0..2 (12 loads)
#pragma unroll
    for (int t = 0; t < 3; t++) {
        const long kb = (long)t * BK;
        unsigned short* base = &lds[t * 16384];
        g2l16(aS0 + kb, base + ldsW);
        g2l16(aS1 + kb, base + 4096 + ldsW);
        g2l16(bS0 + kb, base + 8192 + ldsW);
        g2l16(bS1 + kb, base + 12288 + ldsW);
    }
    // tiles 0,1 landed (8 oldest retired); tile 2 may be in flight.
    asm volatile("s_waitcnt vmcnt(4)" ::: "memory");
    __builtin_amdgcn_sched_barrier(0);
    __builtin_amdgcn_s_barrier();

    bf16x8 afA[4], bfA[4], afB[4], bfB[4], ag[4];
    // read F[0] (tile 0, buf 0): A m0-3 + B n0-3
#pragma unroll
    for (int m = 0; m < 4; m++)
        afA[m] = *(const bf16x8*)&lds[(wm * 128 + m * 16) * 32 + myoff];
#pragma unroll
    for (int n = 0; n < 4; n++)
        bfA[n] = *(const bf16x8*)&lds[8192 + (wn * 64 + n * 16) * 32 + myoff];

    // One K-tile region: stage(kt+3) | read ag(kt) | MFMA m0-3(AC,BC) |
    // read AN/BN(kt+1) | MFMA m4-7(ag,BC) | vmcnt(4) | barrier.
    // Safety: bufs kt&3, (kt+1)&3, (kt+3)&3 pairwise distinct; barrier at
    // end of kt-1 (after vmcnt(4)) guarantees tiles <= kt+1 landed.
#define TILE_STEP(KT, AC, BC, AN, BN)                                          \
    {                                                                          \
        const int kt_   = (KT);                                                \
        const unsigned short* At = &lds[(kt_ & 3) * 16384];                    \
        const unsigned short* Bt = At + 8192;                                  \
        unsigned short* sb = &lds[((kt_ + 3) & 3) * 16384];                    \
        const int st  = (kt_ + 3 < nkt) ? kt_ + 3 : nkt - 1;                   \
        const long kb = (long)st * BK;                                         \
        g2l16(aS0 + kb, sb + ldsW);                                            \
        g2l16(aS1 + kb, sb + 4096 + ldsW);                                     \
        g2l16(bS0 + kb, sb + 8192 + ldsW);                                     \
        g2l16(bS1 + kb, sb + 12288 + ldsW);                                    \
        _Pragma("unroll")                                                      \
        for (int m = 0; m < 4; m++)                                            \
            ag[m] = *(const bf16x8*)&At[(wm * 128 + 64 + m * 16) * 32 + myoff];\
        __builtin_amdgcn_s_setprio(1);                                         \
        _Pragma("unroll")                                                      \
        for (int m = 0; m < 4; m++)                                            \
            _Pragma("unroll")                                                  \
            for (int n = 0; n < 4; n++)                                        \
                acc[m][n] = __builtin_amdgcn_mfma_f32_16x16x32_bf16(           \
                    AC[m], BC[n], acc[m][n], 0, 0, 0);                         \
        __builtin_amdgcn_s_setprio(0);                                         \
        const unsigned short* Atn = &lds[((kt_ + 1) & 3) * 16384];             \
        const unsigned short* Btn = Atn + 8192;                                \
        _Pragma("unroll")                                                      \
        for (int m = 0; m < 4; m++)                                            \
            AN[m] = *(const bf16x8*)&Atn[(wm * 128 + m * 16) * 32 + myoff];    \
        _Pragma("unroll")                                                      \
        for (int n = 0; n < 4; n++)                                            \
            BN[n] = *(const bf16x8*)&Btn[(wn * 64 + n * 16) * 32 + myoff];     \
        __builtin_amdgcn_s_setprio(1);                                         \
        _Pragma("unroll")                                                      \
        for (int m = 0; m < 4; m++)                                            \
            _Pragma("unroll")                                                  \
            for (int n = 0; n < 4; n++)                                        \
                acc[4 + m][n] = __builtin_amdgcn_mfma_f32_16x16x32_bf16(       \
                    ag[m], BC[n], acc[4 + m][n], 0, 0, 0);                     \
        __builtin_amdgcn_s_setprio(0);                                         \
        asm volatile("s_waitcnt vmcnt(4)" ::: "memory");                       \
        __builtin_amdgcn_sched_barrier(0);                                     \
        __builtin_amdgcn_s_barrier();                                          \
    }

    for (int kt = 0; kt < nkt; kt += 2) {
        TILE_STEP(kt,     afA, bfA, afB, bfB);
        TILE_STEP(kt + 1, afB, bfB, afA, bfA);
    }
#undef TILE_STEP

    // ==================== LDS-staged coalesced epilogue ====================
    // Drain dummy re-stage DMAs before reusing LDS.
    asm volatile("s_waitcnt vmcnt(0)" ::: "memory");
    __syncthreads();

    if constexpr (sizeof(OutT) == 2) {
        // bf16: whole 256x256 tile fits (128KB). q4-XOR swizzle keeps the
        // b16 scatter writes conflict-free (verified: 0 conflicts).
#pragma unroll
        for (int m = 0; m < 8; m++)
#pragma unroll
            for (int n = 0; n < 4; n++) {
                const int col = wn * 64 + n * 16 + lr;
#pragma unroll
                for (int r = 0; r < 4; r++) {
                    const int row = wm * 128 + m * 16 + q4 * 4 + r;
                    float v = acc[m][n][r];
                    if constexpr (BIAS_MODE == 1) v += bias[n0 + col];
                    if constexpr (BIAS_MODE == 2) v += bias[m0 + row];
                    v *= scale;
                    lds[row * 256 + (col ^ (((row >> 2) & 3) << 4))] = f2bf(v);
                }
            }
        __syncthreads();
#pragma unroll
        for (int i = 0; i < 16; i++) {
            const int g   = i * 512 + tid;
            const int row = g >> 5;
            const int ch  = g & 31;
            bf16x8 v = *(const bf16x8*)&lds[row * 256 + ((ch * 8) ^ (((row >> 2) & 3) << 4))];
            *(bf16x8*)((unsigned short*)C + (m0 + row) * ldc + n0 + ch * 8) = v;
        }
    } else {
        // f32: two 128-row passes (each 128KB).
        float* fl = (float*)lds;
#pragma unroll
        for (int h = 0; h < 2; h++) {
            __syncthreads();
            if (wm == h) {
#pragma unroll
                for (int m = 0; m < 8; m++)
#pragma unroll
                    for (int n = 0; n < 4; n++) {
                        const int col = wn * 64 + n * 16 + lr;
#pragma unroll
                        for (int r = 0; r < 4; r++) {
                            const int rowh = m * 16 + q4 * 4 + r;   // 0..127
                            float v = acc[m][n][r];
                            if constexpr (BIAS_MODE == 1) v += bias[n0 + col];
                            if constexpr (BIAS_MODE == 2) v += bias[m0 + h * 128 + rowh];
                            v *= scale;
                            fl[rowh * 256 + (col ^ (((rowh >> 2) & 3) << 4))] = v;
                        }
                    }
            }
            __syncthreads();
#pragma unroll
            for (int i = 0; i < 16; i++) {
                const int g   = i * 512 + tid;
                const int row = g >> 6;          // 64 x 16B chunks per 1KB row
                const int ch  = g & 63;
                float4 v = *(const float4*)&fl[row * 256 + ((ch * 4) ^ (((row >> 2) & 3) << 4))];
                *(float4*)((float*)C + (m0 + h * 128 + row) * ldc + n0 + ch * 4) = v;
            }
        }
    }
}

// Fused dual-tensor f32 -> bf16 (RNE), 8 elem/thread/iter, grid-stride.
__global__ __launch_bounds__(256) void cvt2_f32_bf16(
    const float* __restrict__ inA, unsigned short* __restrict__ outA, long n8A,
    const float* __restrict__ inB, unsigned short* __restrict__ outB, long n8B)
{
    const long total  = n8A + n8B;
    const long stride = (long)gridDim.x * blockDim.x;
    for (long i = (long)blockIdx.x * blockDim.x + threadIdx.x; i < total; i += stride) {
        const float* src;
        unsigned short* dst;
        long j;
        if (i < n8A) { src = inA; dst = outA; j = i; }
        else         { src = inB; dst = outB; j = i - n8A; }
        const float4* pp = (const float4*)(src + j * 8);
        float4 a = pp[0], b = pp[1];
        bf16x8 v;
        v[0] = (short)f2bf(a.x); v[1] = (short)f2bf(a.y);
        v[2] = (short)f2bf(a.z); v[3] = (short)f2bf(a.w);
        v[4] = (short)f2bf(b.x); v[5] = (short)f2bf(b.y);
        v[6] = (short)f2bf(b.z); v[7] = (short)f2bf(b.w);
        *(bf16x8*)(dst + j * 8) = v;
    }
}

// In-place softmax on rows of 1024 bf16; f32 math; clamp keeps failures finite.
__global__ __launch_bounds__(256) void softmax_rows(unsigned short* __restrict__ base)
{
    unsigned short* p = base + (long)blockIdx.x * 1024;
    const int tid = threadIdx.x;
    ushort4 u = ((const ushort4*)p)[tid];
    float x0 = bf2f(u.x), x1 = bf2f(u.y), x2 = bf2f(u.z), x3 = bf2f(u.w);
    x0 = fminf(fmaxf(x0, -1e30f), 1e30f);
    x1 = fminf(fmaxf(x1, -1e30f), 1e30f);
    x2 = fminf(fmaxf(x2, -1e30f), 1e30f);
    x3 = fminf(fmaxf(x3, -1e30f), 1e30f);

    float m = fmaxf(fmaxf(x0, x1), fmaxf(x2, x3));
#pragma unroll
    for (int o = 32; o > 0; o >>= 1) m = fmaxf(m, __shfl_xor(m, o));
    __shared__ float redm[4], reds[4];
    const int wave = tid >> 6, lane = tid & 63;
    if (lane == 0) redm[wave] = m;
    __syncthreads();
    m = fmaxf(fmaxf(redm[0], redm[1]), fmaxf(redm[2], redm[3]));

    float e0 = __expf(x0 - m), e1 = __expf(x1 - m);
    float e2 = __expf(x2 - m), e3 = __expf(x3 - m);
    float s = e0 + e1 + e2 + e3;
#pragma unroll
    for (int o = 32; o > 0; o >>= 1) s += __shfl_xor(s, o);
    if (lane == 0) reds[wave] = s;
    __syncthreads();
    s = reds[0] + reds[1] + reds[2] + reds[3];
    const float inv = 1.0f / s;

    ushort4 ov = make_ushort4(f2bf(e0 * inv), f2bf(e1 * inv),
                              f2bf(e2 * inv), f2bf(e3 * inv));
    ((ushort4*)p)[tid] = ov;
}

extern "C" void kernel_launch(void* const* d_in, const int* in_sizes, int n_in,
                              void* d_out, int out_size, void* d_ws, size_t ws_size,
                              hipStream_t stream) {
    const float* query = (const float*)d_in[0];  // (1024,16,1024) f32, rows l*16+n
    const float* keyp  = (const float*)d_in[1];  // rows s*16+n
    const float* valp  = (const float*)d_in[2];
    const float* wq    = (const float*)d_in[3];  // (1024,1024) f32
    const float* wk    = (const float*)d_in[4];
    const float* wv    = (const float*)d_in[5];
    const float* bias  = (const float*)d_in[6];  // (3072,) f32
    float* out = (float*)d_out;                  // 16M f32 = 64 MB

    unsigned short* WSA = (unsigned short*)d_ws;  // 32 MB
    unsigned short* WSB = WSA + 16777216;         // 32 MB
    unsigned short* OC  = (unsigned short*)d_out; // 32 MB (dead before final PV write)
    unsigned short* OD  = OC + 16777216;          // 32 MB

    const dim3 cblk(256, 1, 1);
    const dim3 gblk(512, 1, 1);

    // 1) Q -> bf16 (WSA) + Wq -> bf16 (WSB[0:2MB)) fused
    cvt2_f32_bf16<<<2048, cblk, 0, stream>>>(query, WSA, 2097152, wq, WSB, 131072);
    // 2) Qproj = (Q @ Wq^T + bq) * E^-0.5 -> OC (bf16, rows l*16+n)
    gemm_bt2<1, unsigned short><<<256, gblk, 0, stream>>>(
        WSA, WSB, OC, bias, 0.03125f, 1024,
        1024, 1024, 1024, 0, 0, 0, 64, 4);
    // 3) K -> bf16 (WSA) + Wk -> bf16 (WSB) fused
    cvt2_f32_bf16<<<2048, cblk, 0, stream>>>(keyp, WSA, 2097152, wk, WSB, 131072);
    // 4) Kproj = K @ Wk^T + bk -> OD (bf16, rows s*16+n)
    gemm_bt2<1, unsigned short><<<256, gblk, 0, stream>>>(
        WSA, WSB, OD, bias + 1024, 1.0f, 1024,
        1024, 1024, 1024, 0, 0, 0, 64, 4);
    // 5) scores[n][l][s] = Qproj_n @ Kproj_n^T -> WSB
    gemm_bt2<0, unsigned short><<<256, gblk, 0, stream>>>(
        OC, OD, WSB, nullptr, 1.0f, 1024,
        16384, 16384, 1024, 1024, 1024, 1048576, 4, 4);
    // 6) softmax over s, all 16384 rows, in place
    softmax_rows<<<16384, cblk, 0, stream>>>(WSB);
    // 7) V -> bf16 (OC; Qproj dead) + Wv -> bf16 (OD[0:2MB); Kproj dead) fused
    cvt2_f32_bf16<<<2048, cblk, 0, stream>>>(valp, OC, 2097152, wv, OD, 131072);
    // 8) Vt[n][f][s] = Wv @ V_n^T + bv[f] (row-bias) -> WSA
    gemm_bt2<2, unsigned short><<<256, gblk, 0, stream>>>(
        OD, OC, WSA, bias + 2048, 1.0f, 1024,
        1024, 16384, 1024, 0, 1024, 1048576, 4, 4);
    // 9) out[(l*16+n)][f] = attn_n[l][:] . Vt_n[f][:] -> d_out (f32)
    gemm_bt2<0, float><<<256, gblk, 0, stream>>>(
        WSB, WSA, out, nullptr, 1.0f, 1024,
        1024, 1024, 16384, 1048576, 1048576, 1024, 4, 4);
}

// Round 4
// 425.734 us; speedup vs baseline: 1.0140x; 1.0140x over previous
//
#include <hip/hip_runtime.h>
#include <stdint.h>

// L=S=1024, N=16, E=1024, single head. f32 in/out, bf16 MFMA internally.
//
// R8: TLP-first GEMM engine. Same 256x256 block tile / 128KB ring-4 LDS /
// swizzled g2l16 staging / counted vmcnt as R7, but the block is now ONE
// 1024-thread block = 16 waves (4x4 wave grid, wave-tile 64x64, acc 4x4).
// 4 waves/SIMD instead of 2: ds_read latency, barrier skew and staging
// stalls are hidden by wave-level TLP (m114 mechanism) instead of by
// intra-wave scheduling (R6/R7 showed that is neutral at 2 waves/SIMD).
// Simple m97-style loop: {stage(t+3); read frags(t); 16 MFMA; vmcnt(4);
// barrier}. __launch_bounds__(1024,4) caps VGPR at 128 (acc 64 + frags 32).
// Epilogue/cvt/softmax/XCD-swizzle/launch sequence unchanged from R7.

typedef __attribute__((ext_vector_type(8))) short bf16x8;   // 8 bf16 = 4 VGPRs
typedef __attribute__((ext_vector_type(4))) float f32x4;    // MFMA 16x16 accum

__device__ __forceinline__ float bf2f(unsigned short u) {
    union { unsigned int i; float f; } w; w.i = ((unsigned int)u) << 16; return w.f;
}
__device__ __forceinline__ unsigned short f2bf(float f) {
    union { float f; unsigned int i; } w; w.f = f;
    unsigned int r = (w.i + 0x7FFFu + ((w.i >> 16) & 1u)) >> 16;  // RNE
    return (unsigned short)r;
}

// async global->LDS, 16B/lane; LDS dest is wave-uniform base + lane*16B
__device__ __forceinline__ void g2l16(const unsigned short* g, unsigned short* l) {
    __builtin_amdgcn_global_load_lds(
        (const __attribute__((address_space(1))) unsigned int*)g,
        (__attribute__((address_space(3))) unsigned int*)l, 16, 0, 0);
}

#define BM 256
#define BN 256
#define BK 32

// C[m][col] = (sum_k A[m,k]*B[col,k] + bias) * scale.
// BIAS_MODE: 0 none, 1 per-col, 2 per-row. K multiple of 32, K/32 >= 4.
// Grid MUST be exactly 256 blocks (8 XCDs x 32 chunk).
template <int BIAS_MODE, typename OutT>
__global__ __launch_bounds__(1024, 4) void gemm_bt2(
    const unsigned short* __restrict__ A,
    const unsigned short* __restrict__ B,
    OutT* __restrict__ C,
    const float* __restrict__ bias,
    float scale, int K,
    long lda, long ldb, long ldc,
    long aBatch, long bBatch, long cBatch,
    int gridM, int gridN)
{
    // ring: buf*16384 shorts; A tile at +0 (8192 shorts), B tile at +8192.
    __shared__ __align__(16) unsigned short lds[65536];   // 128 KiB

    const int tid  = threadIdx.x;
    const int wave = tid >> 6;      // 0..15
    const int lane = tid & 63;
    const int lr   = lane & 15;
    const int q4   = lane >> 4;
    const int wm   = wave >> 2;     // 0..3  (M quarter)
    const int wn   = wave & 3;      // 0..3  (N quarter)

    // chunked XCD swizzle: physical p -> logical l; XCD (p%8) owns 32
    // consecutive logical blocks; bcol-fast decode keeps panel sharers
    // on one XCD's L2.
    const int p    = blockIdx.x;
    const int l    = ((p & 7) << 5) + (p >> 3);
    const int bcol = l % gridN;
    const int t2   = l / gridN;
    const int brow = t2 % gridM;
    const int bz   = t2 / gridM;

    const long m0 = (long)brow * BM;
    const long n0 = (long)bcol * BN;
    A += (long)bz * aBatch;
    B += (long)bz * bBatch;
    C += (long)bz * cBatch;

    // staging map: physical 16B chunk pc = tid (0..1023) holds logical chunk
    // lc = pc ^ ((pc>>3)&7) (involution, bits>=3 of the low-6 unchanged,
    // stays within each 1KB 16-row block). row = lc>>2 (0..255),
    // k-chunk = lc&3. One g2l16 per tensor per wave per K-tile.
    const int tswz  = tid ^ ((tid >> 3) & 7);
    const int srow  = tswz >> 2;          // 0..255
    const int skoff = (tswz & 3) * 8;     // element offset in k
    const unsigned short* aS = A + (m0 + srow) * lda + skoff;
    const unsigned short* bS = B + (n0 + srow) * ldb + skoff;
    const int ldsW = wave * 512;          // wave's 1KB slice per stage inst

    // swizzled fragment read offset (lane constant, in ushorts)
    const int myoff = (((lr << 2) | q4) ^ ((lr >> 1) & 7)) << 3;

    f32x4 acc[4][4];
    const f32x4 zero = {0.f, 0.f, 0.f, 0.f};
#pragma unroll
    for (int m = 0; m < 4; m++)
#pragma unroll
        for (int n = 0; n < 4; n++) acc[m][n] = zero;

    const int nkt = K / BK;   // 32 here

    // ---- prologue: stage tiles 0..2 into bufs 0..2 (6 loads/thread-wave)
#pragma unroll
    for (int t = 0; t < 3; t++) {
        const long kb = (long)t * BK;
        unsigned short* base = &lds[t * 16384];
        g2l16(aS + kb, base + ldsW);
        g2l16(bS + kb, base + 8192 + ldsW);
    }
    // newest 4 loads (tiles 1,2) may be in flight; tile 0 landed.
    asm volatile("s_waitcnt vmcnt(4)" ::: "memory");
    __builtin_amdgcn_sched_barrier(0);
    __builtin_amdgcn_s_barrier();

    for (int kt = 0; kt < nkt; kt++) {
        const int buf  = kt & 3;
        const int sbuf = (kt + 3) & 3;                       // read-retired at kt-1
        const int st   = (kt + 3 < nkt) ? kt + 3 : nkt - 1;  // clamp: dummy re-stage
        const long kb  = (long)st * BK;
        const unsigned short* At = &lds[buf * 16384];
        const unsigned short* Bt = At + 8192;
        unsigned short* sb = &lds[sbuf * 16384];

        // issue next-tile staging first (VMEM early)
        g2l16(aS + kb, sb + ldsW);
        g2l16(bS + kb, sb + 8192 + ldsW);

        // fragment reads, just-in-time; TLP (4 waves/SIMD) hides lgkmcnt
        bf16x8 af[4], bfr[4];
#pragma unroll
        for (int m = 0; m < 4; m++)
            af[m] = *(const bf16x8*)&At[(wm * 64 + m * 16) * 32 + myoff];
#pragma unroll
        for (int n = 0; n < 4; n++)
            bfr[n] = *(const bf16x8*)&Bt[(wn * 64 + n * 16) * 32 + myoff];

        __builtin_amdgcn_s_setprio(1);
#pragma unroll
        for (int m = 0; m < 4; m++)
#pragma unroll
            for (int n = 0; n < 4; n++)
                acc[m][n] = __builtin_amdgcn_mfma_f32_16x16x32_bf16(
                    af[m], bfr[n], acc[m][n], 0, 0, 0);
        __builtin_amdgcn_s_setprio(0);

        // counted boundary wait: tiles kt+2,kt+3 (4 loads) may stay in flight;
        // guarantees tile kt+1 fully landed for every wave.
        asm volatile("s_waitcnt vmcnt(4)" ::: "memory");
        __builtin_amdgcn_sched_barrier(0);
        __builtin_amdgcn_s_barrier();
    }

    // ==================== LDS-staged coalesced epilogue ====================
    // Drain dummy re-stage DMAs before reusing LDS.
    asm volatile("s_waitcnt vmcnt(0)" ::: "memory");
    __syncthreads();

    if constexpr (sizeof(OutT) == 2) {
        // bf16: whole 256x256 tile fits (128KB). q4-XOR swizzle keeps the
        // b16 scatter writes conflict-free (verified: 0 conflicts).
#pragma unroll
        for (int m = 0; m < 4; m++)
#pragma unroll
            for (int n = 0; n < 4; n++) {
                const int col = wn * 64 + n * 16 + lr;
#pragma unroll
                for (int r = 0; r < 4; r++) {
                    const int row = wm * 64 + m * 16 + q4 * 4 + r;
                    float v = acc[m][n][r];
                    if constexpr (BIAS_MODE == 1) v += bias[n0 + col];
                    if constexpr (BIAS_MODE == 2) v += bias[m0 + row];
                    v *= scale;
                    lds[row * 256 + (col ^ (((row >> 2) & 3) << 4))] = f2bf(v);
                }
            }
        __syncthreads();
        // 8 sweeps x 16KB: 16B/lane full-line stores.
#pragma unroll
        for (int i = 0; i < 8; i++) {
            const int g   = i * 1024 + tid;
            const int row = g >> 5;
            const int ch  = g & 31;
            bf16x8 v = *(const bf16x8*)&lds[row * 256 + ((ch * 8) ^ (((row >> 2) & 3) << 4))];
            *(bf16x8*)((unsigned short*)C + (m0 + row) * ldc + n0 + ch * 8) = v;
        }
    } else {
        // f32: two 128-row passes (each 128KB).
        float* fl = (float*)lds;
#pragma unroll
        for (int h = 0; h < 2; h++) {
            __syncthreads();
            if ((wm >> 1) == h) {
#pragma unroll
                for (int m = 0; m < 4; m++)
#pragma unroll
                    for (int n = 0; n < 4; n++) {
                        const int col = wn * 64 + n * 16 + lr;
#pragma unroll
                        for (int r = 0; r < 4; r++) {
                            const int rowh = (wm & 1) * 64 + m * 16 + q4 * 4 + r;  // 0..127
                            float v = acc[m][n][r];
                            if constexpr (BIAS_MODE == 1) v += bias[n0 + col];
                            if constexpr (BIAS_MODE == 2) v += bias[m0 + h * 128 + rowh];
                            v *= scale;
                            fl[rowh * 256 + (col ^ (((rowh >> 2) & 3) << 4))] = v;
                        }
                    }
            }
            __syncthreads();
#pragma unroll
            for (int i = 0; i < 8; i++) {
                const int g   = i * 1024 + tid;
                const int row = g >> 6;          // 64 x 16B chunks per 1KB row
                const int ch  = g & 63;
                float4 v = *(const float4*)&fl[row * 256 + ((ch * 4) ^ (((row >> 2) & 3) << 4))];
                *(float4*)((float*)C + (m0 + h * 128 + row) * ldc + n0 + ch * 4) = v;
            }
        }
    }
}

// Fused dual-tensor f32 -> bf16 (RNE), 8 elem/thread/iter, grid-stride.
__global__ __launch_bounds__(256) void cvt2_f32_bf16(
    const float* __restrict__ inA, unsigned short* __restrict__ outA, long n8A,
    const float* __restrict__ inB, unsigned short* __restrict__ outB, long n8B)
{
    const long total  = n8A + n8B;
    const long stride = (long)gridDim.x * blockDim.x;
    for (long i = (long)blockIdx.x * blockDim.x + threadIdx.x; i < total; i += stride) {
        const float* src;
        unsigned short* dst;
        long j;
        if (i < n8A) { src = inA; dst = outA; j = i; }
        else         { src = inB; dst = outB; j = i - n8A; }
        const float4* pp = (const float4*)(src + j * 8);
        float4 a = pp[0], b = pp[1];
        bf16x8 v;
        v[0] = (short)f2bf(a.x); v[1] = (short)f2bf(a.y);
        v[2] = (short)f2bf(a.z); v[3] = (short)f2bf(a.w);
        v[4] = (short)f2bf(b.x); v[5] = (short)f2bf(b.y);
        v[6] = (short)f2bf(b.z); v[7] = (short)f2bf(b.w);
        *(bf16x8*)(dst + j * 8) = v;
    }
}

// In-place softmax on rows of 1024 bf16; f32 math; clamp keeps failures finite.
__global__ __launch_bounds__(256) void softmax_rows(unsigned short* __restrict__ base)
{
    unsigned short* p = base + (long)blockIdx.x * 1024;
    const int tid = threadIdx.x;
    ushort4 u = ((const ushort4*)p)[tid];
    float x0 = bf2f(u.x), x1 = bf2f(u.y), x2 = bf2f(u.z), x3 = bf2f(u.w);
    x0 = fminf(fmaxf(x0, -1e30f), 1e30f);
    x1 = fminf(fmaxf(x1, -1e30f), 1e30f);
    x2 = fminf(fmaxf(x2, -1e30f), 1e30f);
    x3 = fminf(fmaxf(x3, -1e30f), 1e30f);

    float m = fmaxf(fmaxf(x0, x1), fmaxf(x2, x3));
#pragma unroll
    for (int o = 32; o > 0; o >>= 1) m = fmaxf(m, __shfl_xor(m, o));
    __shared__ float redm[4], reds[4];
    const int wave = tid >> 6, lane = tid & 63;
    if (lane == 0) redm[wave] = m;
    __syncthreads();
    m = fmaxf(fmaxf(redm[0], redm[1]), fmaxf(redm[2], redm[3]));

    float e0 = __expf(x0 - m), e1 = __expf(x1 - m);
    float e2 = __expf(x2 - m), e3 = __expf(x3 - m);
    float s = e0 + e1 + e2 + e3;
#pragma unroll
    for (int o = 32; o > 0; o >>= 1) s += __shfl_xor(s, o);
    if (lane == 0) reds[wave] = s;
    __syncthreads();
    s = reds[0] + reds[1] + reds[2] + reds[3];
    const float inv = 1.0f / s;

    ushort4 ov = make_ushort4(f2bf(e0 * inv), f2bf(e1 * inv),
                              f2bf(e2 * inv), f2bf(e3 * inv));
    ((ushort4*)p)[tid] = ov;
}

extern "C" void kernel_launch(void* const* d_in, const int* in_sizes, int n_in,
                              void* d_out, int out_size, void* d_ws, size_t ws_size,
                              hipStream_t stream) {
    const float* query = (const float*)d_in[0];  // (1024,16,1024) f32, rows l*16+n
    const float* keyp  = (const float*)d_in[1];  // rows s*16+n
    const float* valp  = (const float*)d_in[2];
    const float* wq    = (const float*)d_in[3];  // (1024,1024) f32
    const float* wk    = (const float*)d_in[4];
    const float* wv    = (const float*)d_in[5];
    const float* bias  = (const float*)d_in[6];  // (3072,) f32
    float* out = (float*)d_out;                  // 16M f32 = 64 MB

    unsigned short* WSA = (unsigned short*)d_ws;  // 32 MB
    unsigned short* WSB = WSA + 16777216;         // 32 MB
    unsigned short* OC  = (unsigned short*)d_out; // 32 MB (dead before final PV write)
    unsigned short* OD  = OC + 16777216;          // 32 MB

    const dim3 cblk(256, 1, 1);
    const dim3 gblk(1024, 1, 1);

    // 1) Q -> bf16 (WSA) + Wq -> bf16 (WSB[0:2MB)) fused
    cvt2_f32_bf16<<<2048, cblk, 0, stream>>>(query, WSA, 2097152, wq, WSB, 131072);
    // 2) Qproj = (Q @ Wq^T + bq) * E^-0.5 -> OC (bf16, rows l*16+n)
    gemm_bt2<1, unsigned short><<<256, gblk, 0, stream>>>(
        WSA, WSB, OC, bias, 0.03125f, 1024,
        1024, 1024, 1024, 0, 0, 0, 64, 4);
    // 3) K -> bf16 (WSA) + Wk -> bf16 (WSB) fused
    cvt2_f32_bf16<<<2048, cblk, 0, stream>>>(keyp, WSA, 2097152, wk, WSB, 131072);
    // 4) Kproj = K @ Wk^T + bk -> OD (bf16, rows s*16+n)
    gemm_bt2<1, unsigned short><<<256, gblk, 0, stream>>>(
        WSA, WSB, OD, bias + 1024, 1.0f, 1024,
        1024, 1024, 1024, 0, 0, 0, 64, 4);
    // 5) scores[n][l][s] = Qproj_n @ Kproj_n^T -> WSB
    gemm_bt2<0, unsigned short><<<256, gblk, 0, stream>>>(
        OC, OD, WSB, nullptr, 1.0f, 1024,
        16384, 16384, 1024, 1024, 1024, 1048576, 4, 4);
    // 6) softmax over s, all 16384 rows, in place
    softmax_rows<<<16384, cblk, 0, stream>>>(WSB);
    // 7) V -> bf16 (OC; Qproj dead) + Wv -> bf16 (OD[0:2MB); Kproj dead) fused
    cvt2_f32_bf16<<<2048, cblk, 0, stream>>>(valp, OC, 2097152, wv, OD, 131072);
    // 8) Vt[n][f][s] = Wv @ V_n^T + bv[f] (row-bias) -> WSA
    gemm_bt2<2, unsigned short><<<256, gblk, 0, stream>>>(
        OD, OC, WSA, bias + 2048, 1.0f, 1024,
        1024, 16384, 1024, 0, 1024, 1048576, 4, 4);
    // 9) out[(l*16+n)][f] = attn_n[l][:] . Vt_n[f][:] -> d_out (f32)
    gemm_bt2<0, float><<<256, gblk, 0, stream>>>(
        WSB, WSA, out, nullptr, 1.0f, 1024,
        1024, 1024, 16384, 1048576, 1048576, 1024, 4, 4);
}

// Round 5
// 422.544 us; speedup vs baseline: 1.0216x; 1.0076x over previous
//
#include <hip/hip_runtime.h>
#include <stdint.h>

// L=S=1024, N=16, E=1024, single head. f32 in/out, bf16 MFMA internally.
//
// R9 = R8 GEMM engine (unchanged: 1024-thr 16-wave block, 256x256 tile,
// ring-4 LDS, g2l16 staging, counted vmcnt(4), LDS-staged epilogue, XCD
// chunk swizzle) + streaming-side rebuild:
//   1. ONE upfront cvt dispatch (Q,K,Wq,Wk,Wv -> bf16), single-iteration,
//      branch-free per-wave mapping, exact grid.
//   2. Wave-per-row softmax: 1 wave = 1 full row, shuffle-only reduction,
//      no barriers, no LDS, 4096 blocks.
//   3. Buffer re-plan (8 dispatches):
//      cvt_all: WSA<-Qb, WSB<-Kb, OD[0:6MB]<-Wq|Wk|Wv
//      Qproj(WSA,Wq)->OC ; Kproj(WSB,Wk)->WSA ; scores(OC,WSA)->WSB ;
//      softmax WSB ; cvt_v valp->OC ; Vt(Wv,OC)->WSA ; PV(WSB,WSA)->out.

typedef __attribute__((ext_vector_type(8))) short bf16x8;   // 8 bf16 = 4 VGPRs
typedef __attribute__((ext_vector_type(4))) float f32x4;    // MFMA 16x16 accum

__device__ __forceinline__ float bf2f(unsigned short u) {
    union { unsigned int i; float f; } w; w.i = ((unsigned int)u) << 16; return w.f;
}
__device__ __forceinline__ unsigned short f2bf(float f) {
    union { float f; unsigned int i; } w; w.f = f;
    unsigned int r = (w.i + 0x7FFFu + ((w.i >> 16) & 1u)) >> 16;  // RNE
    return (unsigned short)r;
}

// async global->LDS, 16B/lane; LDS dest is wave-uniform base + lane*16B
__device__ __forceinline__ void g2l16(const unsigned short* g, unsigned short* l) {
    __builtin_amdgcn_global_load_lds(
        (const __attribute__((address_space(1))) unsigned int*)g,
        (__attribute__((address_space(3))) unsigned int*)l, 16, 0, 0);
}

#define BM 256
#define BN 256
#define BK 32

// C[m][col] = (sum_k A[m,k]*B[col,k] + bias) * scale.
// BIAS_MODE: 0 none, 1 per-col, 2 per-row. K multiple of 32, K/32 >= 4.
// Grid MUST be exactly 256 blocks (8 XCDs x 32 chunk).
template <int BIAS_MODE, typename OutT>
__global__ __launch_bounds__(1024, 4) void gemm_bt2(
    const unsigned short* __restrict__ A,
    const unsigned short* __restrict__ B,
    OutT* __restrict__ C,
    const float* __restrict__ bias,
    float scale, int K,
    long lda, long ldb, long ldc,
    long aBatch, long bBatch, long cBatch,
    int gridM, int gridN)
{
    // ring: buf*16384 shorts; A tile at +0 (8192 shorts), B tile at +8192.
    __shared__ __align__(16) unsigned short lds[65536];   // 128 KiB

    const int tid  = threadIdx.x;
    const int wave = tid >> 6;      // 0..15
    const int lane = tid & 63;
    const int lr   = lane & 15;
    const int q4   = lane >> 4;
    const int wm   = wave >> 2;     // 0..3  (M quarter)
    const int wn   = wave & 3;      // 0..3  (N quarter)

    // chunked XCD swizzle: physical p -> logical l; XCD (p%8) owns 32
    // consecutive logical blocks; bcol-fast decode keeps panel sharers
    // on one XCD's L2.
    const int p    = blockIdx.x;
    const int l    = ((p & 7) << 5) + (p >> 3);
    const int bcol = l % gridN;
    const int t2   = l / gridN;
    const int brow = t2 % gridM;
    const int bz   = t2 / gridM;

    const long m0 = (long)brow * BM;
    const long n0 = (long)bcol * BN;
    A += (long)bz * aBatch;
    B += (long)bz * bBatch;
    C += (long)bz * cBatch;

    // staging map: physical 16B chunk pc = tid (0..1023) holds logical chunk
    // lc = pc ^ ((pc>>3)&7) (involution). row = lc>>2 (0..255), k-chunk = lc&3.
    const int tswz  = tid ^ ((tid >> 3) & 7);
    const int srow  = tswz >> 2;          // 0..255
    const int skoff = (tswz & 3) * 8;     // element offset in k
    const unsigned short* aS = A + (m0 + srow) * lda + skoff;
    const unsigned short* bS = B + (n0 + srow) * ldb + skoff;
    const int ldsW = wave * 512;          // wave's 1KB slice per stage inst

    // swizzled fragment read offset (lane constant, in ushorts)
    const int myoff = (((lr << 2) | q4) ^ ((lr >> 1) & 7)) << 3;

    f32x4 acc[4][4];
    const f32x4 zero = {0.f, 0.f, 0.f, 0.f};
#pragma unroll
    for (int m = 0; m < 4; m++)
#pragma unroll
        for (int n = 0; n < 4; n++) acc[m][n] = zero;

    const int nkt = K / BK;   // 32 here

    // ---- prologue: stage tiles 0..2 into bufs 0..2
#pragma unroll
    for (int t = 0; t < 3; t++) {
        const long kb = (long)t * BK;
        unsigned short* base = &lds[t * 16384];
        g2l16(aS + kb, base + ldsW);
        g2l16(bS + kb, base + 8192 + ldsW);
    }
    // newest 4 loads (tiles 1,2) may be in flight; tile 0 landed.
    asm volatile("s_waitcnt vmcnt(4)" ::: "memory");
    __builtin_amdgcn_sched_barrier(0);
    __builtin_amdgcn_s_barrier();

    for (int kt = 0; kt < nkt; kt++) {
        const int buf  = kt & 3;
        const int sbuf = (kt + 3) & 3;                       // read-retired at kt-1
        const int st   = (kt + 3 < nkt) ? kt + 3 : nkt - 1;  // clamp: dummy re-stage
        const long kb  = (long)st * BK;
        const unsigned short* At = &lds[buf * 16384];
        const unsigned short* Bt = At + 8192;
        unsigned short* sb = &lds[sbuf * 16384];

        // issue next-tile staging first (VMEM early)
        g2l16(aS + kb, sb + ldsW);
        g2l16(bS + kb, sb + 8192 + ldsW);

        // fragment reads, just-in-time; TLP (4 waves/SIMD) hides lgkmcnt
        bf16x8 af[4], bfr[4];
#pragma unroll
        for (int m = 0; m < 4; m++)
            af[m] = *(const bf16x8*)&At[(wm * 64 + m * 16) * 32 + myoff];
#pragma unroll
        for (int n = 0; n < 4; n++)
            bfr[n] = *(const bf16x8*)&Bt[(wn * 64 + n * 16) * 32 + myoff];

        __builtin_amdgcn_s_setprio(1);
#pragma unroll
        for (int m = 0; m < 4; m++)
#pragma unroll
            for (int n = 0; n < 4; n++)
                acc[m][n] = __builtin_amdgcn_mfma_f32_16x16x32_bf16(
                    af[m], bfr[n], acc[m][n], 0, 0, 0);
        __builtin_amdgcn_s_setprio(0);

        // counted boundary wait: tiles kt+2,kt+3 (4 loads) may stay in flight;
        // guarantees tile kt+1 fully landed for every wave.
        asm volatile("s_waitcnt vmcnt(4)" ::: "memory");
        __builtin_amdgcn_sched_barrier(0);
        __builtin_amdgcn_s_barrier();
    }

    // ==================== LDS-staged coalesced epilogue ====================
    // Drain dummy re-stage DMAs before reusing LDS.
    asm volatile("s_waitcnt vmcnt(0)" ::: "memory");
    __syncthreads();

    if constexpr (sizeof(OutT) == 2) {
        // bf16: whole 256x256 tile fits (128KB). q4-XOR swizzle keeps the
        // b16 scatter writes conflict-free (verified: 0 conflicts).
#pragma unroll
        for (int m = 0; m < 4; m++)
#pragma unroll
            for (int n = 0; n < 4; n++) {
                const int col = wn * 64 + n * 16 + lr;
#pragma unroll
                for (int r = 0; r < 4; r++) {
                    const int row = wm * 64 + m * 16 + q4 * 4 + r;
                    float v = acc[m][n][r];
                    if constexpr (BIAS_MODE == 1) v += bias[n0 + col];
                    if constexpr (BIAS_MODE == 2) v += bias[m0 + row];
                    v *= scale;
                    lds[row * 256 + (col ^ (((row >> 2) & 3) << 4))] = f2bf(v);
                }
            }
        __syncthreads();
        // 8 sweeps x 16KB: 16B/lane full-line stores.
#pragma unroll
        for (int i = 0; i < 8; i++) {
            const int g   = i * 1024 + tid;
            const int row = g >> 5;
            const int ch  = g & 31;
            bf16x8 v = *(const bf16x8*)&lds[row * 256 + ((ch * 8) ^ (((row >> 2) & 3) << 4))];
            *(bf16x8*)((unsigned short*)C + (m0 + row) * ldc + n0 + ch * 8) = v;
        }
    } else {
        // f32: two 128-row passes (each 128KB).
        float* fl = (float*)lds;
#pragma unroll
        for (int h = 0; h < 2; h++) {
            __syncthreads();
            if ((wm >> 1) == h) {
#pragma unroll
                for (int m = 0; m < 4; m++)
#pragma unroll
                    for (int n = 0; n < 4; n++) {
                        const int col = wn * 64 + n * 16 + lr;
#pragma unroll
                        for (int r = 0; r < 4; r++) {
                            const int rowh = (wm & 1) * 64 + m * 16 + q4 * 4 + r;  // 0..127
                            float v = acc[m][n][r];
                            if constexpr (BIAS_MODE == 1) v += bias[n0 + col];
                            if constexpr (BIAS_MODE == 2) v += bias[m0 + h * 128 + rowh];
                            v *= scale;
                            fl[rowh * 256 + (col ^ (((rowh >> 2) & 3) << 4))] = v;
                        }
                    }
            }
            __syncthreads();
#pragma unroll
            for (int i = 0; i < 8; i++) {
                const int g   = i * 1024 + tid;
                const int row = g >> 6;          // 64 x 16B chunks per 1KB row
                const int ch  = g & 63;
                float4 v = *(const float4*)&fl[row * 256 + ((ch * 4) ^ (((row >> 2) & 3) << 4))];
                *(float4*)((float*)C + (m0 + h * 128 + row) * ldc + n0 + ch * 4) = v;
            }
        }
    }
}

// Upfront conversion: Q (8192 blocks), K (8192), Wq|Wk|Wv (512 each).
// Single iteration per thread: 32B load, 16B store, exact grid = 17920.
__global__ __launch_bounds__(256) void cvt_all(
    const float* __restrict__ q,  unsigned short* __restrict__ qb,
    const float* __restrict__ k,  unsigned short* __restrict__ kb,
    const float* __restrict__ wq, const float* __restrict__ wk,
    const float* __restrict__ wv, unsigned short* __restrict__ wb)
{
    const int b = blockIdx.x;
    const float* src;
    unsigned short* dst;
    long item;
    if (b < 8192)       { src = q; dst = qb; item = (long)b * 256 + threadIdx.x; }
    else if (b < 16384) { src = k; dst = kb; item = (long)(b - 8192) * 256 + threadIdx.x; }
    else {
        const int wsel = (b - 16384) >> 9;      // 0,1,2
        src = (wsel == 0) ? wq : ((wsel == 1) ? wk : wv);
        dst = wb + (long)wsel * 1048576;
        item = (long)((b - 16384) & 511) * 256 + threadIdx.x;
    }
    const float4* pp = (const float4*)(src + item * 8);
    float4 a = pp[0], c = pp[1];
    bf16x8 v;
    v[0] = (short)f2bf(a.x); v[1] = (short)f2bf(a.y);
    v[2] = (short)f2bf(a.z); v[3] = (short)f2bf(a.w);
    v[4] = (short)f2bf(c.x); v[5] = (short)f2bf(c.y);
    v[6] = (short)f2bf(c.z); v[7] = (short)f2bf(c.w);
    *(bf16x8*)(dst + item * 8) = v;
}

// Single-tensor f32 -> bf16, single iteration, exact grid (n/2048 blocks).
__global__ __launch_bounds__(256) void cvt_one(
    const float* __restrict__ in, unsigned short* __restrict__ out)
{
    const long item = (long)blockIdx.x * 256 + threadIdx.x;
    const float4* pp = (const float4*)(in + item * 8);
    float4 a = pp[0], c = pp[1];
    bf16x8 v;
    v[0] = (short)f2bf(a.x); v[1] = (short)f2bf(a.y);
    v[2] = (short)f2bf(a.z); v[3] = (short)f2bf(a.w);
    v[4] = (short)f2bf(c.x); v[5] = (short)f2bf(c.y);
    v[6] = (short)f2bf(c.z); v[7] = (short)f2bf(c.w);
    *(bf16x8*)(out + item * 8) = v;
}

// Wave-per-row softmax: 1 wave owns a full 1024-elem bf16 row. 16 elems/lane,
// shuffle-only reduction, no barriers, no LDS. Grid = 4096 blocks x 4 waves.
__global__ __launch_bounds__(256) void softmax_wave(unsigned short* __restrict__ base)
{
    const int wave = threadIdx.x >> 6, lane = threadIdx.x & 63;
    unsigned short* p = base + ((long)blockIdx.x * 4 + wave) * 1024;

    bf16x8 v0 = *(const bf16x8*)(p + lane * 8);
    bf16x8 v1 = *(const bf16x8*)(p + 512 + lane * 8);
    float x[16];
#pragma unroll
    for (int i = 0; i < 8; i++) {
        x[i]     = fminf(fmaxf(bf2f((unsigned short)v0[i]), -1e30f), 1e30f);
        x[8 + i] = fminf(fmaxf(bf2f((unsigned short)v1[i]), -1e30f), 1e30f);
    }
    float m = x[0];
#pragma unroll
    for (int i = 1; i < 16; i++) m = fmaxf(m, x[i]);
#pragma unroll
    for (int o = 32; o > 0; o >>= 1) m = fmaxf(m, __shfl_xor(m, o));

    float e[16], s = 0.f;
#pragma unroll
    for (int i = 0; i < 16; i++) { e[i] = __expf(x[i] - m); s += e[i]; }
#pragma unroll
    for (int o = 32; o > 0; o >>= 1) s += __shfl_xor(s, o);
    const float inv = 1.0f / s;

    bf16x8 o0, o1;
#pragma unroll
    for (int i = 0; i < 8; i++) {
        o0[i] = (short)f2bf(e[i] * inv);
        o1[i] = (short)f2bf(e[8 + i] * inv);
    }
    *(bf16x8*)(p + lane * 8) = o0;
    *(bf16x8*)(p + 512 + lane * 8) = o1;
}

extern "C" void kernel_launch(void* const* d_in, const int* in_sizes, int n_in,
                              void* d_out, int out_size, void* d_ws, size_t ws_size,
                              hipStream_t stream) {
    const float* query = (const float*)d_in[0];  // (1024,16,1024) f32, rows l*16+n
    const float* keyp  = (const float*)d_in[1];  // rows s*16+n
    const float* valp  = (const float*)d_in[2];
    const float* wq    = (const float*)d_in[3];  // (1024,1024) f32
    const float* wk    = (const float*)d_in[4];
    const float* wv    = (const float*)d_in[5];
    const float* bias  = (const float*)d_in[6];  // (3072,) f32
    float* out = (float*)d_out;                  // 16M f32 = 64 MB

    unsigned short* WSA = (unsigned short*)d_ws;  // 32 MB
    unsigned short* WSB = WSA + 16777216;         // 32 MB
    unsigned short* OC  = (unsigned short*)d_out; // 32 MB
    unsigned short* OD  = OC + 16777216;          // 32 MB

    const dim3 cblk(256, 1, 1);
    const dim3 gblk(1024, 1, 1);

    // 1) cvt_all: Qb->WSA, Kb->WSB, Wq|Wk|Wv -> OD[0:6MB)
    cvt_all<<<17920, cblk, 0, stream>>>(query, WSA, keyp, WSB, wq, wk, wv, OD);
    // 2) Qproj = (Qb @ Wq^T + bq) * E^-0.5 -> OC (bf16, rows l*16+n)
    gemm_bt2<1, unsigned short><<<256, gblk, 0, stream>>>(
        WSA, OD, OC, bias, 0.03125f, 1024,
        1024, 1024, 1024, 0, 0, 0, 64, 4);
    // 3) Kproj = Kb @ Wk^T + bk -> WSA (Qb dead)
    gemm_bt2<1, unsigned short><<<256, gblk, 0, stream>>>(
        WSB, OD + 1048576, WSA, bias + 1024, 1.0f, 1024,
        1024, 1024, 1024, 0, 0, 0, 64, 4);
    // 4) scores[n][l][s] = Qproj_n @ Kproj_n^T -> WSB (Kb dead)
    gemm_bt2<0, unsigned short><<<256, gblk, 0, stream>>>(
        OC, WSA, WSB, nullptr, 1.0f, 1024,
        16384, 16384, 1024, 1024, 1024, 1048576, 4, 4);
    // 5) softmax over s, all 16384 rows, in place (wave-per-row)
    softmax_wave<<<4096, cblk, 0, stream>>>(WSB);
    // 6) Vb = bf16(valp) -> OC (Qproj dead)
    cvt_one<<<8192, cblk, 0, stream>>>(valp, OC);
    // 7) Vt[n][f][s] = Wv @ Vb_n^T + bv[f] (row-bias) -> WSA (Kproj dead)
    gemm_bt2<2, unsigned short><<<256, gblk, 0, stream>>>(
        OD + 2097152, OC, WSA, bias + 2048, 1.0f, 1024,
        1024, 16384, 1024, 0, 1024, 1048576, 4, 4);
    // 8) out[(l*16+n)][f] = attn_n[l][:] . Vt_n[f][:] -> d_out (f32)
    gemm_bt2<0, float><<<256, gblk, 0, stream>>>(
        WSB, WSA, out, nullptr, 1.0f, 1024,
        1024, 1024, 16384, 1048576, 1048576, 1024, 4, 4);
}